// Round 1
// baseline (158.412 us; speedup 1.0000x reference)
//
#include <hip/hip_runtime.h>
#include <math.h>

#define D 64
#define KNOTS 32
#define NSEG 31
#define STR 33  // padded LDS stride (bank-conflict-free)

// --- Precompute kernel: one block, one thread per dim ---
// Computes A[d][s] = m*scale, B[d][s] = (y0 - m*x0)*scale + shift into d_ws.
__global__ __launch_bounds__(64) void pwl_precompute(
    const float* __restrict__ xk, const float* __restrict__ delta_raw,
    const float* __restrict__ scale_raw, const float* __restrict__ shift,
    float* __restrict__ AB) {
  int d = threadIdx.x;
  if (d >= D) return;

  float kx[KNOTS];
#pragma unroll
  for (int j = 0; j < KNOTS; ++j) kx[j] = xk[d * KNOTS + j];

  float sl[NSEG], dx[NSEG];
  float num = 0.f, den = 0.f;
#pragma unroll
  for (int s = 0; s < NSEG; ++s) {
    float dr = delta_raw[d * NSEG + s];
    // stable softplus: max(x,0) + log1p(exp(-|x|))
    float sp = fmaxf(dr, 0.f) + log1pf(expf(-fabsf(dr)));
    sl[s] = sp + 1e-4f;
    dx[s] = kx[s + 1] - kx[s];
    num += sl[s] * dx[s];
    den += dx[s];
  }
  float avg = fmaxf(num / (den + 1e-8f), 1e-6f);

  float sr = scale_raw[d];
  float scale = fmaxf(sr, 0.f) + log1pf(expf(-fabsf(sr))) + 1e-3f;
  float sh = shift[d];

  float y = 0.f;
#pragma unroll
  for (int s = 0; s < NSEG; ++s) {
    float m = sl[s] / avg;
    AB[d * 2 * NSEG + s] = m * scale;                          // A
    AB[d * 2 * NSEG + NSEG + s] = (y - m * kx[s]) * scale + sh; // B
    y += m * dx[s];
  }
}

// --- Main kernel: grid-stride over float2 elements ---
// Each thread owns a fixed pair of dims (d0, d0+1) since stride % 64 == 0.
__global__ __launch_bounds__(256) void pwl_eval(
    const float* __restrict__ x, const float* __restrict__ xk,
    const float* __restrict__ AB, float* __restrict__ out, int nvec) {
  __shared__ float s_xk[D * STR];
  __shared__ float s_A[D * STR];
  __shared__ float s_B[D * STR];

  for (int i = threadIdx.x; i < D * KNOTS; i += blockDim.x) {
    int d = i >> 5, j = i & 31;
    s_xk[d * STR + j] = xk[i];
  }
  for (int i = threadIdx.x; i < D * NSEG; i += blockDim.x) {
    int d = i / NSEG, s = i - d * NSEG;
    s_A[d * STR + s] = AB[d * 2 * NSEG + s];
    s_B[d * STR + s] = AB[d * 2 * NSEG + NSEG + s];
  }
  __syncthreads();

  const int d0 = (2 * threadIdx.x) & 63;
  const float* __restrict__ t0 = s_xk + d0 * STR;
  const float* __restrict__ t1 = s_xk + (d0 + 1) * STR;
  const float* __restrict__ A0 = s_A + d0 * STR;
  const float* __restrict__ B0 = s_B + d0 * STR;
  const float* __restrict__ A1 = s_A + (d0 + 1) * STR;
  const float* __restrict__ B1 = s_B + (d0 + 1) * STR;

  const int stride = gridDim.x * blockDim.x;
  for (int v = blockIdx.x * blockDim.x + threadIdx.x; v < nvec; v += stride) {
    float2 xv = reinterpret_cast<const float2*>(x)[v];

    // branchless lower_bound (searchsorted side='left'), probes indices 0..30:
    // result = min(#knots < x, 31); reference clips to [1,31] then -1 anyway.
    int b0 = 0, b1 = 0;
#pragma unroll
    for (int half = 16; half > 0; half >>= 1) {
      b0 += (t0[b0 + half - 1] < xv.x) ? half : 0;
      b1 += (t1[b1 + half - 1] < xv.y) ? half : 0;
    }
    int s0 = (b0 > 0 ? b0 : 1) - 1;  // clamp to [0,30]
    int s1 = (b1 > 0 ? b1 : 1) - 1;

    float2 r;
    r.x = fmaf(A0[s0], xv.x, B0[s0]);
    r.y = fmaf(A1[s1], xv.y, B1[s1]);
    reinterpret_cast<float2*>(out)[v] = r;
  }
}

extern "C" void kernel_launch(void* const* d_in, const int* in_sizes, int n_in,
                              void* d_out, int out_size, void* d_ws, size_t ws_size,
                              hipStream_t stream) {
  const float* x = (const float*)d_in[0];          // [N, D]
  const float* xk = (const float*)d_in[1];         // [D, K]
  const float* delta_raw = (const float*)d_in[2];  // [D, K-1]
  const float* scale_raw = (const float*)d_in[3];  // [D]
  const float* shift = (const float*)d_in[4];      // [D]
  float* out = (float*)d_out;
  float* AB = (float*)d_ws;  // [D][2*NSEG]

  pwl_precompute<<<1, 64, 0, stream>>>(xk, delta_raw, scale_raw, shift, AB);

  const int total = in_sizes[0];      // N*D = 64,000,000
  const int nvec = total / 2;         // float2 elements
  const int block = 256;
  const int grid = 2048;              // 256 CU * 8 blocks, grid-stride
  pwl_eval<<<grid, block, 0, stream>>>(x, xk, AB, out, nvec);
}

// Round 2
// 149.948 us; speedup vs baseline: 1.0564x; 1.0564x over previous
//
#include <hip/hip_runtime.h>
#include <math.h>

#define D 64
#define KNOTS 32
#define NSEG 31

// --- Precompute kernel: one block, one thread per dim ---
// Writes A,B in [seg][dim] layout: A[s*D+d] = m*scale,
// B[NSEG*D + s*D + d] = (y0 - m*x0)*scale + shift.
__global__ __launch_bounds__(64) void pwl_precompute(
    const float* __restrict__ xk, const float* __restrict__ delta_raw,
    const float* __restrict__ scale_raw, const float* __restrict__ shift,
    float* __restrict__ AB) {
  int d = threadIdx.x;
  if (d >= D) return;

  float kx[KNOTS];
#pragma unroll
  for (int j = 0; j < KNOTS; ++j) kx[j] = xk[d * KNOTS + j];

  float sl[NSEG], dx[NSEG];
  float num = 0.f, den = 0.f;
#pragma unroll
  for (int s = 0; s < NSEG; ++s) {
    float dr = delta_raw[d * NSEG + s];
    // stable softplus: max(x,0) + log1p(exp(-|x|))
    float sp = fmaxf(dr, 0.f) + log1pf(expf(-fabsf(dr)));
    sl[s] = sp + 1e-4f;
    dx[s] = kx[s + 1] - kx[s];
    num += sl[s] * dx[s];
    den += dx[s];
  }
  float avg = fmaxf(num / (den + 1e-8f), 1e-6f);

  float sr = scale_raw[d];
  float scale = fmaxf(sr, 0.f) + log1pf(expf(-fabsf(sr))) + 1e-3f;
  float sh = shift[d];

  float y = 0.f;
#pragma unroll
  for (int s = 0; s < NSEG; ++s) {
    float m = sl[s] / avg;
    AB[s * D + d] = m * scale;                                  // A
    AB[NSEG * D + s * D + d] = (y - m * kx[s]) * scale + sh;    // B
    y += m * dx[s];
  }
}

// --- Main kernel ---
// Lane l owns dim l: a wave's 64 lanes cover one row of x (256 B, coalesced).
// Knots live in 32 VGPRs per lane; segment index by unrolled compare-count
// (no LDS search chain). LDS only holds A/B in [seg][dim] layout so the
// final gather is bank = lane%32 -> 2-way (free).
__global__ __launch_bounds__(256, 6) void pwl_eval(
    const float* __restrict__ x, const float* __restrict__ xk,
    const float* __restrict__ AB, float* __restrict__ out, int nrows) {
  __shared__ float s_A[NSEG * D];
  __shared__ float s_B[NSEG * D];
  const int lane = threadIdx.x & 63;

  // Stage xk transposed into s_A ([j][d]), read per-lane knots, then reuse
  // s_A for the A table.
  for (int i = threadIdx.x; i < D * KNOTS; i += blockDim.x) {
    int d = i >> 5, j = i & 31;
    s_A[j * D + d] = xk[i];
  }
  __syncthreads();
  float k[KNOTS];
#pragma unroll
  for (int j = 0; j < KNOTS; ++j) k[j] = s_A[j * D + lane];
  __syncthreads();
  for (int i = threadIdx.x; i < NSEG * D; i += blockDim.x) {
    s_A[i] = AB[i];
    s_B[i] = AB[NSEG * D + i];
  }
  __syncthreads();

  const int gwave = (blockIdx.x * blockDim.x + threadIdx.x) >> 6;
  const int nwave = (gridDim.x * blockDim.x) >> 6;
  const int ngroups = nrows >> 2;  // 4 rows per wave-iteration

  for (int g = gwave; g < ngroups; g += nwave) {
    const int base = g * (4 * D) + lane;
    float x0 = x[base];
    float x1 = x[base + D];
    float x2 = x[base + 2 * D];
    float x3 = x[base + 3 * D];

    // i0 = min(#{j in [1,31]: k[j] < x}, 30)  ==  clip(searchsorted,1,31)-1
    int i0 = 0, i1 = 0, i2 = 0, i3 = 0;
#pragma unroll
    for (int j = 1; j < KNOTS; ++j) {
      i0 += k[j] < x0;
      i1 += k[j] < x1;
      i2 += k[j] < x2;
      i3 += k[j] < x3;
    }
    i0 = min(i0, 30); i1 = min(i1, 30); i2 = min(i2, 30); i3 = min(i3, 30);

    float r0 = fmaf(s_A[i0 * D + lane], x0, s_B[i0 * D + lane]);
    float r1 = fmaf(s_A[i1 * D + lane], x1, s_B[i1 * D + lane]);
    float r2 = fmaf(s_A[i2 * D + lane], x2, s_B[i2 * D + lane]);
    float r3 = fmaf(s_A[i3 * D + lane], x3, s_B[i3 * D + lane]);

    out[base] = r0;
    out[base + D] = r1;
    out[base + 2 * D] = r2;
    out[base + 3 * D] = r3;
  }

  // tail rows (nrows % 4 != 0) — one row per wave-iteration
  for (int r = (ngroups << 2) + gwave; r < nrows; r += nwave) {
    const int base = r * D + lane;
    float xv = x[base];
    int i0 = 0;
#pragma unroll
    for (int j = 1; j < KNOTS; ++j) i0 += k[j] < xv;
    i0 = min(i0, 30);
    out[base] = fmaf(s_A[i0 * D + lane], xv, s_B[i0 * D + lane]);
  }
}

extern "C" void kernel_launch(void* const* d_in, const int* in_sizes, int n_in,
                              void* d_out, int out_size, void* d_ws, size_t ws_size,
                              hipStream_t stream) {
  const float* x = (const float*)d_in[0];          // [N, D]
  const float* xk = (const float*)d_in[1];         // [D, K]
  const float* delta_raw = (const float*)d_in[2];  // [D, K-1]
  const float* scale_raw = (const float*)d_in[3];  // [D]
  const float* shift = (const float*)d_in[4];      // [D]
  float* out = (float*)d_out;
  float* AB = (float*)d_ws;  // [2][NSEG][D]

  pwl_precompute<<<1, 64, 0, stream>>>(xk, delta_raw, scale_raw, shift, AB);

  const int nrows = in_sizes[0] / D;  // 1,000,000
  const int block = 256;
  const int grid = 2048;              // grid-stride over row-groups
  pwl_eval<<<grid, block, 0, stream>>>(x, xk, AB, out, nrows);
}